// Round 2
// baseline (1686.731 us; speedup 1.0000x reference)
//
#include <hip/hip_runtime.h>

#define NN 200000
#define NE 3200000
static constexpr float EPSV = 1e-5f;

// ---------------- CSR build ----------------
__global__ void k_hist(const int* __restrict__ ei, int* __restrict__ deg){
  int e = blockIdx.x*blockDim.x + threadIdx.x;
  if (e < NE) atomicAdd(&deg[ei[NE + e]], 1);
}

__global__ void k_scanA(const int* __restrict__ deg, int* __restrict__ part){
  __shared__ int s[1024];
  int t = threadIdx.x; int i = blockIdx.x*1024 + t;
  s[t] = (i < NN) ? deg[i] : 0;
  __syncthreads();
  for (int o = 512; o > 0; o >>= 1){ if (t < o) s[t] += s[t+o]; __syncthreads(); }
  if (t == 0) part[blockIdx.x] = s[0];
}

__global__ void k_scanB(int* __restrict__ part, int nb){
  if (threadIdx.x == 0 && blockIdx.x == 0){
    int run = 0;
    for (int i = 0; i < nb; ++i){ int v = part[i]; part[i] = run; run += v; }
  }
}

__global__ void k_scanC(int* __restrict__ degcur, const int* __restrict__ part,
                        int* __restrict__ off){
  __shared__ int s[1024];
  int t = threadIdx.x; int i = blockIdx.x*1024 + t;
  int v = (i < NN) ? degcur[i] : 0;
  s[t] = v; __syncthreads();
  for (int o = 1; o < 1024; o <<= 1){
    int xv = 0; if (t >= o) xv = s[t-o];
    __syncthreads(); s[t] += xv; __syncthreads();
  }
  int excl = s[t] - v + part[blockIdx.x];
  if (i < NN){ off[i] = excl; degcur[i] = excl; }
  if (i == 0) off[NN] = NE;
}

__global__ void k_scatter(const int* __restrict__ ei, int* __restrict__ cur,
                          int* __restrict__ srcs){
  int e = blockIdx.x*blockDim.x + threadIdx.x;
  if (e < NE){
    int d = ei[NE + e];
    int p = atomicAdd(&cur[d], 1);
    srcs[p] = ei[e];
  }
}

// ---------------- Block 1 (N=200000, C=16) ----------------
__global__ void k_prep1(const float* __restrict__ x, const float* __restrict__ pos,
                        const float* __restrict__ w, float* __restrict__ A,
                        float* __restrict__ xstats){
  int i = blockIdx.x*blockDim.x + threadIdx.x;
  float xf = 0.f;
  if (i < NN){
    xf = x[i];
    float px = pos[3*i], py = pos[3*i+1];
    #pragma unroll
    for (int c = 0; c < 16; ++c){
      A[i*16+c] = xf*w[c] + px*w[16+c] + py*w[32+c];
    }
  }
  __shared__ float sv[256], sq[256];
  int t = threadIdx.x;
  float v = (i < NN) ? xf : 0.f;
  sv[t] = v; sq[t] = v*v; __syncthreads();
  for (int o = 128; o > 0; o >>= 1){
    if (t < o){ sv[t]+=sv[t+o]; sq[t]+=sq[t+o]; } __syncthreads();
  }
  if (t == 0){ atomicAdd(&xstats[0], sv[0]); atomicAdd(&xstats[1], sq[0]); }
}

// CSR gather-max, C=16: 16 lanes per dst.
__global__ void k_agg16(const float* __restrict__ A, const int* __restrict__ srcs,
                        const int* __restrict__ off, const float* __restrict__ pos,
                        const float* __restrict__ wpos, const float* __restrict__ bias,
                        float* __restrict__ H, float* __restrict__ st){
  int t = threadIdx.x;
  int lane = t & 15;
  int d = blockIdx.x*16 + (t >> 4);   // NN divisible by 16
  int s0 = off[d], s1 = off[d+1];
  float m = -__builtin_inff();
  for (int j = s0; j < s1; ++j){
    int s = srcs[j];
    m = fmaxf(m, A[s*16 + lane]);
  }
  float val = 0.f;
  if (s1 > s0){
    float px = pos[3*d], py = pos[3*d+1];
    float B = bias[lane] - (px*wpos[lane] + py*wpos[16+lane]);
    val = m + B;
  }
  H[d*16 + lane] = val;
  __shared__ float sv[256], sq[256];
  sv[t] = val; sq[t] = val*val; __syncthreads();
  for (int o = 128; o >= 16; o >>= 1){
    if (t < o){ sv[t]+=sv[t+o]; sq[t]+=sq[t+o]; } __syncthreads();
  }
  if (t < 16){ atomicAdd(&st[t], sv[t]); atomicAdd(&st[16+t], sq[t]); }
}

__global__ void k_bnrelu(float* __restrict__ H, const float* __restrict__ st,
                         int n, int C, int doRelu){
  int idx = blockIdx.x*blockDim.x + threadIdx.x;
  if (idx >= n*C) return;
  int c = idx % C;
  float inv_n = 1.f / (float)n;
  float mean = st[c]*inv_n;
  float var  = st[C+c]*inv_n - mean*mean;
  float inv  = rsqrtf(var + EPSV);
  float v = (H[idx] - mean)*inv;
  if (doRelu) v = fmaxf(v, 0.f);
  H[idx] = v;
}

__global__ void k_prep2(const float* __restrict__ Hin, const float* __restrict__ pos,
                        const float* __restrict__ w, float* __restrict__ A){
  int idx = blockIdx.x*blockDim.x + threadIdx.x;
  if (idx >= NN*16) return;
  int i = idx >> 4, c = idx & 15;
  float acc = 0.f;
  #pragma unroll
  for (int k = 0; k < 16; ++k) acc += Hin[i*16+k]*w[k*16+c];
  float px = pos[3*i], py = pos[3*i+1];
  acc += px*w[256+c] + py*w[272+c];
  A[idx] = acc;
}

__global__ void k_combine1(const float* __restrict__ H, const float* __restrict__ x,
                           const float* __restrict__ lw, const float* __restrict__ st2,
                           const float* __restrict__ xstats, float* __restrict__ O){
  int idx = blockIdx.x*blockDim.x + threadIdx.x;
  if (idx >= NN*16) return;
  int i = idx >> 4, c = idx & 15;
  float inv_n = 1.f/(float)NN;
  float m2 = st2[c]*inv_n, var2 = st2[16+c]*inv_n - m2*m2;
  float i2 = rsqrtf(var2 + EPSV);
  float mx = xstats[0]*inv_n, vx = xstats[1]*inv_n - mx*mx;
  float a = lw[c];
  float sc = a * rsqrtf(a*a*vx + EPSV);
  float v = (H[idx]-m2)*i2 + (x[i]-mx)*sc;
  O[idx] = fmaxf(v, 0.f);
}

__global__ void k_pool1(const float* __restrict__ O, const float* __restrict__ pos,
                        float* __restrict__ mem){
  int idx = blockIdx.x*blockDim.x + threadIdx.x;
  if (idx >= NN*16) return;
  int i = idx >> 4, c = idx & 15;
  float px = pos[3*i], py = pos[3*i+1];
  int cx = (int)(px * 80.f / 240.f); cx = min(max(cx,0),79);
  int cy = (int)(py * 60.f / 180.f); cy = min(max(cy,0),59);
  atomicAdd(&mem[(cy*80+cx)*16 + c], O[idx]);
}

__global__ void k_poollin(const float* __restrict__ mem, const float* __restrict__ W,
                          const float* __restrict__ b, float* __restrict__ G,
                          int n, int C){
  int idx = blockIdx.x*blockDim.x + threadIdx.x;
  if (idx >= n*C) return;
  int i = idx / C, c = idx % C;
  float acc = b[c];
  for (int k = 0; k < C; ++k) acc += mem[i*C+k]*W[k*C+c];
  G[idx] = (acc > 1.f) ? acc : 0.f;
}

// ---------------- Grid blocks (2..4) ----------------
__global__ void k_gmm(const float* __restrict__ X, const float* __restrict__ W,
                      const float* __restrict__ bias, float* __restrict__ S,
                      int n, int K, int C, float* __restrict__ st){
  int idx = blockIdx.x*blockDim.x + threadIdx.x;
  int t = threadIdx.x;
  float val = 0.f;
  if (idx < n*C){
    int i = idx / C, c = idx % C;
    float acc = bias ? bias[c] : 0.f;
    for (int k = 0; k < K; ++k) acc += X[i*K+k]*W[k*C+c];
    S[idx] = acc;
    val = acc;
  }
  if (st){
    __shared__ float sv[256], sq[256];
    sv[t] = val; sq[t] = val*val; __syncthreads();
    for (int o = 128; o >= C; o >>= 1){
      if (t < o){ sv[t]+=sv[t+o]; sq[t]+=sq[t+o]; } __syncthreads();
    }
    if (t < C){ atomicAdd(&st[t], sv[t]); atomicAdd(&st[C+t], sq[t]); }
  }
}

__global__ void k_gridagg(const float* __restrict__ S, const float* __restrict__ wpos,
                          const float* __restrict__ bias, float* __restrict__ H,
                          float* __restrict__ st, int n, int gw, int gh, int C,
                          float sx, float sy){
  int idx = blockIdx.x*blockDim.x + threadIdx.x;
  int t = threadIdx.x;
  float val = 0.f;
  if (idx < n*C){
    int i = idx / C, c = idx % C;
    int x = i % gw, y = i / gw;
    float wx = wpos[c], wy = wpos[C+c];
    float m = -__builtin_inff();
    for (int oy = -1; oy <= 1; ++oy){
      int ny = y + oy; if (ny < 0 || ny >= gh) continue;
      for (int ox = -1; ox <= 1; ++ox){
        int nx = x + ox; if (nx < 0 || nx >= gw) continue;
        float v = S[(ny*gw+nx)*C + c] + (ox*sx)*wx + (oy*sy)*wy;
        m = fmaxf(m, v);
      }
    }
    val = m + bias[c];
    H[idx] = val;
  }
  __shared__ float sv[256], sq[256];
  sv[t] = val; sq[t] = val*val; __syncthreads();
  for (int o = 128; o >= C; o >>= 1){
    if (t < o){ sv[t]+=sv[t+o]; sq[t]+=sq[t+o]; } __syncthreads();
  }
  if (t < C){ atomicAdd(&st[t], sv[t]); atomicAdd(&st[C+t], sq[t]); }
}

__global__ void k_gcombine(const float* __restrict__ H, const float* __restrict__ SK,
                           const float* __restrict__ st2, const float* __restrict__ stsk,
                           float* __restrict__ G, float* __restrict__ outf,
                           int n, int C){
  int idx = blockIdx.x*blockDim.x + threadIdx.x;
  if (idx >= n*C) return;
  int c = idx % C;
  float inv_n = 1.f/(float)n;
  float m2 = st2[c]*inv_n, v2 = st2[C+c]*inv_n - m2*m2;
  float i2 = rsqrtf(v2 + EPSV);
  float ms = stsk[c]*inv_n, vs = stsk[C+c]*inv_n - ms*ms;
  float is_ = rsqrtf(vs + EPSV);
  float v = (H[idx]-m2)*i2 + (SK[idx]-ms)*is_;
  v = fmaxf(v, 0.f);
  if (G) G[idx] = v;
  outf[idx] = v;
}

__global__ void k_pool2x2(const float* __restrict__ G, float* __restrict__ mem,
                          int gw, int gh, int C){
  int ow = gw >> 1;
  int n2 = ow*(gh>>1);
  int idx = blockIdx.x*blockDim.x + threadIdx.x;
  if (idx >= n2*C) return;
  int i = idx / C, c = idx % C;
  int x = i % ow, y = i / ow;
  float a0 = G[((2*y)*gw + 2*x)*C + c];
  float a1 = G[((2*y)*gw + 2*x+1)*C + c];
  float a2 = G[((2*y+1)*gw + 2*x)*C + c];
  float a3 = G[((2*y+1)*gw + 2*x+1)*C + c];
  mem[idx] = ((a0 + a1) + a2) + a3;
}

extern "C" void kernel_launch(void* const* d_in, const int* in_sizes, int n_in,
                              void* d_out, int out_size, void* d_ws, size_t ws_size,
                              hipStream_t stream){
  const float* x   = (const float*)d_in[0];
  const float* pos = (const float*)d_in[1];
  const int*   ei  = (const int*)d_in[2];
  const float* b1_c1w = (const float*)d_in[3];
  const float* b1_c1b = (const float*)d_in[4];
  const float* b1_c2w = (const float*)d_in[5];
  const float* b1_c2b = (const float*)d_in[6];
  const float* b1_lw  = (const float*)d_in[7];
  const float* b2_c1w = (const float*)d_in[9];
  const float* b2_c1b = (const float*)d_in[10];
  const float* b2_c2w = (const float*)d_in[11];
  const float* b2_c2b = (const float*)d_in[12];
  const float* b2_lw  = (const float*)d_in[13];
  const float* b2_lb  = (const float*)d_in[14];
  const float* b3_c1w = (const float*)d_in[15];
  const float* b3_c1b = (const float*)d_in[16];
  const float* b3_c2w = (const float*)d_in[17];
  const float* b3_c2b = (const float*)d_in[18];
  const float* b3_lw  = (const float*)d_in[19];
  const float* b3_lb  = (const float*)d_in[20];
  const float* b4_c1w = (const float*)d_in[21];
  const float* b4_c1b = (const float*)d_in[22];
  const float* b4_c2w = (const float*)d_in[23];
  const float* b4_c2b = (const float*)d_in[24];
  const float* b4_lw  = (const float*)d_in[25];
  const float* b4_lb  = (const float*)d_in[26];
  const float* p1w = (const float*)d_in[27];
  const float* p1b = (const float*)d_in[28];
  const float* p2w = (const float*)d_in[29];
  const float* p2b = (const float*)d_in[30];
  const float* p3w = (const float*)d_in[31];
  const float* p3b = (const float*)d_in[32];
  float* out = (float*)d_out;

  // ---- workspace carve ----
  int* off  = (int*)d_ws;            // NN+1
  int* cur  = off + (NN+1);          // NN
  int* srcs = cur + NN;              // NE
  int* part = srcs + NE;             // 256
  float* A  = (float*)(part + 256);  // NN*16
  float* H  = A + NN*16;             // NN*16
  float* ST = H + NN*16;             // 2048 floats of stats
  float* xstats = ST;
  float* st1    = ST + 16;
  float* st2    = ST + 64;
  float* stB2sk = ST + 128;
  float* stB2c1 = ST + 192;
  float* stB2c2 = ST + 256;
  float* stB3sk = ST + 320;
  float* stB3c1 = ST + 448;
  float* stB3c2 = ST + 576;
  float* stB4sk = ST + 704;
  float* stB4c1 = ST + 960;
  float* stB4c2 = ST + 1216;
  float* SM   = ST + 2048;
  float* mem1 = SM;                  // 4800*16
  float* g1   = mem1 + 76800;
  float* b2S  = g1 + 76800;          // 4800*32
  float* b2SK = b2S + 153600;
  float* b2H  = b2SK + 153600;
  float* g2f  = b2H + 153600;
  float* mem2 = g2f + 153600;        // 1200*32
  float* g2p  = mem2 + 38400;
  float* b3S  = g2p + 38400;         // 1200*64
  float* b3SK = b3S + 76800;
  float* b3H  = b3SK + 76800;
  float* g3f  = b3H + 76800;
  float* mem3 = g3f + 76800;         // 300*64
  float* g3p  = mem3 + 19200;
  float* b4S  = g3p + 19200;         // 300*128
  float* b4SK = b4S + 38400;
  float* b4H  = b4SK + 38400;

  hipMemsetAsync(cur, 0, NN*sizeof(int), stream);
  hipMemsetAsync(ST, 0, 2048*sizeof(float), stream);
  hipMemsetAsync(mem1, 0, 76800*sizeof(float), stream);

  const int B = 256;
  // CSR build
  k_hist   <<<(NE+B-1)/B, B, 0, stream>>>(ei, cur);
  k_scanA  <<<196, 1024, 0, stream>>>(cur, part);
  k_scanB  <<<1, 64, 0, stream>>>(part, 196);
  k_scanC  <<<196, 1024, 0, stream>>>(cur, part, off);
  k_scatter<<<(NE+B-1)/B, B, 0, stream>>>(ei, cur, srcs);

  // Block 1
  k_prep1   <<<(NN+B-1)/B, B, 0, stream>>>(x, pos, b1_c1w, A, xstats);
  k_agg16   <<<NN/16, B, 0, stream>>>(A, srcs, off, pos, b1_c1w+16, b1_c1b, H, st1);
  k_bnrelu  <<<(NN*16+B-1)/B, B, 0, stream>>>(H, st1, NN, 16, 1);
  k_prep2   <<<(NN*16+B-1)/B, B, 0, stream>>>(H, pos, b1_c2w, A);
  k_agg16   <<<NN/16, B, 0, stream>>>(A, srcs, off, pos, b1_c2w+256, b1_c2b, H, st2);
  k_combine1<<<(NN*16+B-1)/B, B, 0, stream>>>(H, x, b1_lw, st2, xstats, A);
  k_pool1   <<<(NN*16+B-1)/B, B, 0, stream>>>(A, pos, mem1);
  k_poollin <<<(4800*16+B-1)/B, B, 0, stream>>>(mem1, p1w, p1b, g1, 4800, 16);

  // Block 2 (80x60 grid, 16->32)
  k_gmm     <<<(4800*32+B-1)/B, B, 0, stream>>>(g1, b2_lw, b2_lb, b2SK, 4800, 16, 32, stB2sk);
  k_gmm     <<<(4800*32+B-1)/B, B, 0, stream>>>(g1, b2_c1w, nullptr, b2S, 4800, 16, 32, nullptr);
  k_gridagg <<<(4800*32+B-1)/B, B, 0, stream>>>(b2S, b2_c1w+16*32, b2_c1b, b2H, stB2c1, 4800, 80, 60, 32, 3.f, 3.f);
  k_bnrelu  <<<(4800*32+B-1)/B, B, 0, stream>>>(b2H, stB2c1, 4800, 32, 1);
  k_gmm     <<<(4800*32+B-1)/B, B, 0, stream>>>(b2H, b2_c2w, nullptr, b2S, 4800, 32, 32, nullptr);
  k_gridagg <<<(4800*32+B-1)/B, B, 0, stream>>>(b2S, b2_c2w+32*32, b2_c2b, b2H, stB2c2, 4800, 80, 60, 32, 3.f, 3.f);
  k_gcombine<<<(4800*32+B-1)/B, B, 0, stream>>>(b2H, b2SK, stB2c2, stB2sk, g2f, out, 4800, 32);
  k_pool2x2 <<<(1200*32+B-1)/B, B, 0, stream>>>(g2f, mem2, 80, 60, 32);
  k_poollin <<<(1200*32+B-1)/B, B, 0, stream>>>(mem2, p2w, p2b, g2p, 1200, 32);

  // Block 3 (40x30 grid, 32->64)
  k_gmm     <<<(1200*64+B-1)/B, B, 0, stream>>>(g2p, b3_lw, b3_lb, b3SK, 1200, 32, 64, stB3sk);
  k_gmm     <<<(1200*64+B-1)/B, B, 0, stream>>>(g2p, b3_c1w, nullptr, b3S, 1200, 32, 64, nullptr);
  k_gridagg <<<(1200*64+B-1)/B, B, 0, stream>>>(b3S, b3_c1w+32*64, b3_c1b, b3H, stB3c1, 1200, 40, 30, 64, 6.f, 6.f);
  k_bnrelu  <<<(1200*64+B-1)/B, B, 0, stream>>>(b3H, stB3c1, 1200, 64, 1);
  k_gmm     <<<(1200*64+B-1)/B, B, 0, stream>>>(b3H, b3_c2w, nullptr, b3S, 1200, 64, 64, nullptr);
  k_gridagg <<<(1200*64+B-1)/B, B, 0, stream>>>(b3S, b3_c2w+64*64, b3_c2b, b3H, stB3c2, 1200, 40, 30, 64, 6.f, 6.f);
  k_gcombine<<<(1200*64+B-1)/B, B, 0, stream>>>(b3H, b3SK, stB3c2, stB3sk, g3f, out+153600, 1200, 64);
  k_pool2x2 <<<(300*64+B-1)/B, B, 0, stream>>>(g3f, mem3, 40, 30, 64);
  k_poollin <<<(300*64+B-1)/B, B, 0, stream>>>(mem3, p3w, p3b, g3p, 300, 64);

  // Block 4 (20x15 grid, 64->128)
  k_gmm     <<<(300*128+B-1)/B, B, 0, stream>>>(g3p, b4_lw, b4_lb, b4SK, 300, 64, 128, stB4sk);
  k_gmm     <<<(300*128+B-1)/B, B, 0, stream>>>(g3p, b4_c1w, nullptr, b4S, 300, 64, 128, nullptr);
  k_gridagg <<<(300*128+B-1)/B, B, 0, stream>>>(b4S, b4_c1w+64*128, b4_c1b, b4H, stB4c1, 300, 20, 15, 128, 12.f, 12.f);
  k_bnrelu  <<<(300*128+B-1)/B, B, 0, stream>>>(b4H, stB4c1, 300, 128, 1);
  k_gmm     <<<(300*128+B-1)/B, B, 0, stream>>>(b4H, b4_c2w, nullptr, b4S, 300, 128, 128, nullptr);
  k_gridagg <<<(300*128+B-1)/B, B, 0, stream>>>(b4S, b4_c2w+128*128, b4_c2b, b4H, stB4c2, 300, 20, 15, 128, 12.f, 12.f);
  k_gcombine<<<(300*128+B-1)/B, B, 0, stream>>>(b4H, b4SK, stB4c2, stB4sk, nullptr, out+230400, 300, 128);
}

// Round 3
// 1094.370 us; speedup vs baseline: 1.5413x; 1.5413x over previous
//
#include <hip/hip_runtime.h>

#define NN 200000
#define NE 3200000
static constexpr float EPSV = 1e-5f;

// ---------------- CSR build ----------------
__global__ void k_hist(const int* __restrict__ ei, int* __restrict__ deg){
  int e = blockIdx.x*blockDim.x + threadIdx.x;
  if (e < NE) atomicAdd(&deg[ei[NE + e]], 1);
}

__global__ void k_scanA(const int* __restrict__ deg, int* __restrict__ part){
  __shared__ int s[1024];
  int t = threadIdx.x; int i = blockIdx.x*1024 + t;
  s[t] = (i < NN) ? deg[i] : 0;
  __syncthreads();
  for (int o = 512; o > 0; o >>= 1){ if (t < o) s[t] += s[t+o]; __syncthreads(); }
  if (t == 0) part[blockIdx.x] = s[0];
}

__global__ void k_scanB(int* __restrict__ part, int nb){
  if (threadIdx.x == 0 && blockIdx.x == 0){
    int run = 0;
    for (int i = 0; i < nb; ++i){ int v = part[i]; part[i] = run; run += v; }
  }
}

__global__ void k_scanC(int* __restrict__ degcur, const int* __restrict__ part,
                        int* __restrict__ off){
  __shared__ int s[1024];
  int t = threadIdx.x; int i = blockIdx.x*1024 + t;
  int v = (i < NN) ? degcur[i] : 0;
  s[t] = v; __syncthreads();
  for (int o = 1; o < 1024; o <<= 1){
    int xv = 0; if (t >= o) xv = s[t-o];
    __syncthreads(); s[t] += xv; __syncthreads();
  }
  int excl = s[t] - v + part[blockIdx.x];
  if (i < NN){ off[i] = excl; degcur[i] = excl; }
  if (i == 0) off[NN] = NE;
}

__global__ void k_scatter(const int* __restrict__ ei, int* __restrict__ cur,
                          int* __restrict__ srcs){
  int e = blockIdx.x*blockDim.x + threadIdx.x;
  if (e < NE){
    int d = ei[NE + e];
    int p = atomicAdd(&cur[d], 1);
    srcs[p] = ei[e];
  }
}

// ---------------- Block 1 (N=200000, C=16) ----------------
__global__ void k_prep1(const float* __restrict__ x, const float* __restrict__ pos,
                        const float* __restrict__ w, float* __restrict__ A,
                        float* __restrict__ xstats){
  int i = blockIdx.x*blockDim.x + threadIdx.x;
  float xf = 0.f;
  if (i < NN){
    xf = x[i];
    float px = pos[3*i], py = pos[3*i+1];
    #pragma unroll
    for (int c = 0; c < 16; ++c){
      A[i*16+c] = xf*w[c] + px*w[16+c] + py*w[32+c];
    }
  }
  __shared__ float sv[256], sq[256];
  int t = threadIdx.x;
  float v = (i < NN) ? xf : 0.f;
  sv[t] = v; sq[t] = v*v; __syncthreads();
  for (int o = 128; o > 0; o >>= 1){
    if (t < o){ sv[t]+=sv[t+o]; sq[t]+=sq[t+o]; } __syncthreads();
  }
  if (t == 0){ atomicAdd(&xstats[0], sv[0]); atomicAdd(&xstats[1], sq[0]); }
}

// CSR gather-max: 64 lanes per dst, 16 edges in flight, float4 channels.
__global__ void k_agg16w(const float4* __restrict__ A4, const int* __restrict__ srcs,
                         const int* __restrict__ off, const float* __restrict__ pos,
                         const float* __restrict__ wpos, const float* __restrict__ bias,
                         float4* __restrict__ H4){
  int t = threadIdx.x;
  int lane = t & 63;
  int d = blockIdx.x*4 + (t >> 6);
  int eidx = lane >> 2;     // 0..15
  int cg = lane & 3;        // channel group (4 ch each)
  int s0 = off[d], s1 = off[d+1];
  float NI = -__builtin_inff();
  float4 m = make_float4(NI, NI, NI, NI);
  for (int j = s0 + eidx; j < s1; j += 16){
    int s = srcs[j];
    float4 a = A4[s*4 + cg];
    m.x = fmaxf(m.x, a.x); m.y = fmaxf(m.y, a.y);
    m.z = fmaxf(m.z, a.z); m.w = fmaxf(m.w, a.w);
  }
  #pragma unroll
  for (int mask = 4; mask <= 32; mask <<= 1){
    m.x = fmaxf(m.x, __shfl_xor(m.x, mask, 64));
    m.y = fmaxf(m.y, __shfl_xor(m.y, mask, 64));
    m.z = fmaxf(m.z, __shfl_xor(m.z, mask, 64));
    m.w = fmaxf(m.w, __shfl_xor(m.w, mask, 64));
  }
  if (eidx == 0){
    float4 val = make_float4(0.f, 0.f, 0.f, 0.f);
    if (s1 > s0){
      float px = pos[3*d], py = pos[3*d+1];
      int c0 = cg*4;
      val.x = m.x + bias[c0+0] - (px*wpos[c0+0] + py*wpos[16+c0+0]);
      val.y = m.y + bias[c0+1] - (px*wpos[c0+1] + py*wpos[16+c0+1]);
      val.z = m.z + bias[c0+2] - (px*wpos[c0+2] + py*wpos[16+c0+2]);
      val.w = m.w + bias[c0+3] - (px*wpos[c0+3] + py*wpos[16+c0+3]);
    }
    H4[d*4 + cg] = val;
  }
}

// per-channel sum/sumsq over H (n*16 elems), low-contention
__global__ void k_stats16(const float* __restrict__ H, float* __restrict__ st){
  int t = threadIdx.x;
  float s = 0.f, q = 0.f;
  for (int idx = blockIdx.x*256 + t; idx < NN*16; idx += gridDim.x*256){
    float v = H[idx]; s += v; q += v*v;
  }
  __shared__ float sv[256], sq[256];
  sv[t] = s; sq[t] = q; __syncthreads();
  for (int o = 128; o >= 16; o >>= 1){
    if (t < o){ sv[t]+=sv[t+o]; sq[t]+=sq[t+o]; } __syncthreads();
  }
  if (t < 16){ atomicAdd(&st[t], sv[t]); atomicAdd(&st[16+t], sq[t]); }
}

// A2 = relu(bn(Hraw)) @ c2w[0:16] + p . c2w[16:18], thread per (node, ch-group)
__global__ void k_prep2(const float* __restrict__ Hraw, const float* __restrict__ st1,
                        const float* __restrict__ pos, const float* __restrict__ w,
                        float4* __restrict__ A4){
  int idx = blockIdx.x*blockDim.x + threadIdx.x;
  if (idx >= NN*4) return;
  int i = idx >> 2, cg = idx & 3;
  const float inv_n = 1.f/(float)NN;
  float acc0 = 0.f, acc1 = 0.f, acc2 = 0.f, acc3 = 0.f;
  #pragma unroll
  for (int k = 0; k < 16; ++k){
    float mk = st1[k]*inv_n;
    float vk = st1[16+k]*inv_n - mk*mk;
    float ik = rsqrtf(vk + EPSV);
    float h = fmaxf((Hraw[i*16+k]-mk)*ik, 0.f);
    acc0 += h*w[k*16 + cg*4 + 0];
    acc1 += h*w[k*16 + cg*4 + 1];
    acc2 += h*w[k*16 + cg*4 + 2];
    acc3 += h*w[k*16 + cg*4 + 3];
  }
  float px = pos[3*i], py = pos[3*i+1];
  int c0 = cg*4;
  acc0 += px*w[256+c0+0] + py*w[272+c0+0];
  acc1 += px*w[256+c0+1] + py*w[272+c0+1];
  acc2 += px*w[256+c0+2] + py*w[272+c0+2];
  acc3 += px*w[256+c0+3] + py*w[272+c0+3];
  A4[idx] = make_float4(acc0, acc1, acc2, acc3);
}

// out = relu(bn(h2pre)+bn_skip) fused with pool1 atomics (no O materialization)
__global__ void k_comb_pool(const float* __restrict__ H, const float* __restrict__ x,
                            const float* __restrict__ pos, const float* __restrict__ lw,
                            const float* __restrict__ st2, const float* __restrict__ xstats,
                            float* __restrict__ mem){
  int idx = blockIdx.x*blockDim.x + threadIdx.x;
  if (idx >= NN*4) return;
  int i = idx >> 2, cg = idx & 3;
  const float inv_n = 1.f/(float)NN;
  float mx = xstats[0]*inv_n, vx = xstats[1]*inv_n - mx*mx;
  float xc = x[i] - mx;
  float px = pos[3*i], py = pos[3*i+1];
  int cx = (int)(px * 80.f / 240.f); cx = min(max(cx,0),79);
  int cy = (int)(py * 60.f / 180.f); cy = min(max(cy,0),59);
  float* mrow = &mem[(cy*80+cx)*16 + cg*4];
  #pragma unroll
  for (int k = 0; k < 4; ++k){
    int c = cg*4 + k;
    float m2 = st2[c]*inv_n, v2 = st2[16+c]*inv_n - m2*m2;
    float i2 = rsqrtf(v2 + EPSV);
    float a = lw[c];
    float sc = a * rsqrtf(a*a*vx + EPSV);
    float v = (H[i*16+c]-m2)*i2 + xc*sc;
    v = fmaxf(v, 0.f);
    atomicAdd(&mrow[k], v);
  }
}

__global__ void k_poollin(const float* __restrict__ mem, const float* __restrict__ W,
                          const float* __restrict__ b, float* __restrict__ G,
                          int n, int C){
  int idx = blockIdx.x*blockDim.x + threadIdx.x;
  if (idx >= n*C) return;
  int i = idx / C, c = idx % C;
  float acc = b[c];
  for (int k = 0; k < C; ++k) acc += mem[i*C+k]*W[k*C+c];
  G[idx] = (acc > 1.f) ? acc : 0.f;
}

// ---------------- Grid blocks (2..4) ----------------
// S = f(X) @ W [+bias]; f = identity, or relu(bn(.)) when instats given.
__global__ void k_gmm(const float* __restrict__ X, const float* __restrict__ W,
                      const float* __restrict__ bias, float* __restrict__ S,
                      int n, int K, int C, float* __restrict__ st,
                      const float* __restrict__ instats){
  int idx = blockIdx.x*blockDim.x + threadIdx.x;
  int t = threadIdx.x;
  float val = 0.f;
  const float inv_n = 1.f/(float)n;
  if (idx < n*C){
    int i = idx / C, c = idx % C;
    float acc = bias ? bias[c] : 0.f;
    for (int k = 0; k < K; ++k){
      float xk = X[i*K+k];
      if (instats){
        float mk = instats[k]*inv_n;
        float vk = instats[K+k]*inv_n - mk*mk;
        xk = fmaxf((xk-mk)*rsqrtf(vk+EPSV), 0.f);
      }
      acc += xk*W[k*C+c];
    }
    S[idx] = acc;
    val = acc;
  }
  if (st){
    __shared__ float sv[256], sq[256];
    sv[t] = val; sq[t] = val*val; __syncthreads();
    for (int o = 128; o >= C; o >>= 1){
      if (t < o){ sv[t]+=sv[t+o]; sq[t]+=sq[t+o]; } __syncthreads();
    }
    if (t < C){ atomicAdd(&st[t], sv[t]); atomicAdd(&st[C+t], sq[t]); }
  }
}

__global__ void k_gridagg(const float* __restrict__ S, const float* __restrict__ wpos,
                          const float* __restrict__ bias, float* __restrict__ H,
                          float* __restrict__ st, int n, int gw, int gh, int C,
                          float sx, float sy){
  int idx = blockIdx.x*blockDim.x + threadIdx.x;
  int t = threadIdx.x;
  float val = 0.f;
  if (idx < n*C){
    int i = idx / C, c = idx % C;
    int x = i % gw, y = i / gw;
    float wx = wpos[c], wy = wpos[C+c];
    float m = -__builtin_inff();
    for (int oy = -1; oy <= 1; ++oy){
      int ny = y + oy; if (ny < 0 || ny >= gh) continue;
      for (int ox = -1; ox <= 1; ++ox){
        int nx = x + ox; if (nx < 0 || nx >= gw) continue;
        float v = S[(ny*gw+nx)*C + c] + (ox*sx)*wx + (oy*sy)*wy;
        m = fmaxf(m, v);
      }
    }
    val = m + bias[c];
    H[idx] = val;
  }
  __shared__ float sv[256], sq[256];
  sv[t] = val; sq[t] = val*val; __syncthreads();
  for (int o = 128; o >= C; o >>= 1){
    if (t < o){ sv[t]+=sv[t+o]; sq[t]+=sq[t+o]; } __syncthreads();
  }
  if (t < C){ atomicAdd(&st[t], sv[t]); atomicAdd(&st[C+t], sq[t]); }
}

__global__ void k_gcombine(const float* __restrict__ H, const float* __restrict__ SK,
                           const float* __restrict__ st2, const float* __restrict__ stsk,
                           float* __restrict__ G, float* __restrict__ outf,
                           int n, int C){
  int idx = blockIdx.x*blockDim.x + threadIdx.x;
  if (idx >= n*C) return;
  int c = idx % C;
  float inv_n = 1.f/(float)n;
  float m2 = st2[c]*inv_n, v2 = st2[C+c]*inv_n - m2*m2;
  float i2 = rsqrtf(v2 + EPSV);
  float ms = stsk[c]*inv_n, vs = stsk[C+c]*inv_n - ms*ms;
  float is_ = rsqrtf(vs + EPSV);
  float v = (H[idx]-m2)*i2 + (SK[idx]-ms)*is_;
  v = fmaxf(v, 0.f);
  if (G) G[idx] = v;
  outf[idx] = v;
}

__global__ void k_pool2x2(const float* __restrict__ G, float* __restrict__ mem,
                          int gw, int gh, int C){
  int ow = gw >> 1;
  int n2 = ow*(gh>>1);
  int idx = blockIdx.x*blockDim.x + threadIdx.x;
  if (idx >= n2*C) return;
  int i = idx / C, c = idx % C;
  int x = i % ow, y = i / ow;
  float a0 = G[((2*y)*gw + 2*x)*C + c];
  float a1 = G[((2*y)*gw + 2*x+1)*C + c];
  float a2 = G[((2*y+1)*gw + 2*x)*C + c];
  float a3 = G[((2*y+1)*gw + 2*x+1)*C + c];
  mem[idx] = ((a0 + a1) + a2) + a3;
}

extern "C" void kernel_launch(void* const* d_in, const int* in_sizes, int n_in,
                              void* d_out, int out_size, void* d_ws, size_t ws_size,
                              hipStream_t stream){
  const float* x   = (const float*)d_in[0];
  const float* pos = (const float*)d_in[1];
  const int*   ei  = (const int*)d_in[2];
  const float* b1_c1w = (const float*)d_in[3];
  const float* b1_c1b = (const float*)d_in[4];
  const float* b1_c2w = (const float*)d_in[5];
  const float* b1_c2b = (const float*)d_in[6];
  const float* b1_lw  = (const float*)d_in[7];
  const float* b2_c1w = (const float*)d_in[9];
  const float* b2_c1b = (const float*)d_in[10];
  const float* b2_c2w = (const float*)d_in[11];
  const float* b2_c2b = (const float*)d_in[12];
  const float* b2_lw  = (const float*)d_in[13];
  const float* b2_lb  = (const float*)d_in[14];
  const float* b3_c1w = (const float*)d_in[15];
  const float* b3_c1b = (const float*)d_in[16];
  const float* b3_c2w = (const float*)d_in[17];
  const float* b3_c2b = (const float*)d_in[18];
  const float* b3_lw  = (const float*)d_in[19];
  const float* b3_lb  = (const float*)d_in[20];
  const float* b4_c1w = (const float*)d_in[21];
  const float* b4_c1b = (const float*)d_in[22];
  const float* b4_c2w = (const float*)d_in[23];
  const float* b4_c2b = (const float*)d_in[24];
  const float* b4_lw  = (const float*)d_in[25];
  const float* b4_lb  = (const float*)d_in[26];
  const float* p1w = (const float*)d_in[27];
  const float* p1b = (const float*)d_in[28];
  const float* p2w = (const float*)d_in[29];
  const float* p2b = (const float*)d_in[30];
  const float* p3w = (const float*)d_in[31];
  const float* p3b = (const float*)d_in[32];
  float* out = (float*)d_out;

  // ---- workspace carve: floats first (16B alignment for float4) ----
  float* A  = (float*)d_ws;          // NN*16
  float* H  = A + NN*16;             // NN*16
  float* ST = H + NN*16;             // 2048 floats of stats
  float* xstats = ST;
  float* st1    = ST + 16;
  float* st2    = ST + 64;
  float* stB2sk = ST + 128;
  float* stB2c1 = ST + 192;
  float* stB2c2 = ST + 256;
  float* stB3sk = ST + 320;
  float* stB3c1 = ST + 448;
  float* stB3c2 = ST + 576;
  float* stB4sk = ST + 704;
  float* stB4c1 = ST + 960;
  float* stB4c2 = ST + 1216;
  float* SM   = ST + 2048;
  float* mem1 = SM;                  // 4800*16
  float* g1   = mem1 + 76800;
  float* b2S  = g1 + 76800;          // 4800*32
  float* b2SK = b2S + 153600;
  float* b2H  = b2SK + 153600;
  float* g2f  = b2H + 153600;
  float* mem2 = g2f + 153600;        // 1200*32
  float* g2p  = mem2 + 38400;
  float* b3S  = g2p + 38400;         // 1200*64
  float* b3SK = b3S + 76800;
  float* b3H  = b3SK + 76800;
  float* g3f  = b3H + 76800;
  float* mem3 = g3f + 76800;         // 300*64
  float* g3p  = mem3 + 19200;
  float* b4S  = g3p + 19200;         // 300*128
  float* b4SK = b4S + 38400;
  float* b4H  = b4SK + 38400;        // end floats
  int* off  = (int*)(b4H + 38400);   // NN+1
  int* cur  = off + (NN+1);          // NN
  int* srcs = cur + NN;              // NE
  int* part = srcs + NE;             // 256

  hipMemsetAsync(cur, 0, NN*sizeof(int), stream);
  hipMemsetAsync(ST, 0, 2048*sizeof(float), stream);
  hipMemsetAsync(mem1, 0, 76800*sizeof(float), stream);

  const int B = 256;
  // CSR build
  k_hist   <<<(NE+B-1)/B, B, 0, stream>>>(ei, cur);
  k_scanA  <<<196, 1024, 0, stream>>>(cur, part);
  k_scanB  <<<1, 64, 0, stream>>>(part, 196);
  k_scanC  <<<196, 1024, 0, stream>>>(cur, part, off);
  k_scatter<<<(NE+B-1)/B, B, 0, stream>>>(ei, cur, srcs);

  // Block 1
  k_prep1   <<<(NN+B-1)/B, B, 0, stream>>>(x, pos, b1_c1w, A, xstats);
  k_agg16w  <<<NN/4, B, 0, stream>>>((const float4*)A, srcs, off, pos, b1_c1w+16, b1_c1b, (float4*)H);
  k_stats16 <<<256, B, 0, stream>>>(H, st1);
  k_prep2   <<<(NN*4+B-1)/B, B, 0, stream>>>(H, st1, pos, b1_c2w, (float4*)A);
  k_agg16w  <<<NN/4, B, 0, stream>>>((const float4*)A, srcs, off, pos, b1_c2w+256, b1_c2b, (float4*)H);
  k_stats16 <<<256, B, 0, stream>>>(H, st2);
  k_comb_pool<<<(NN*4+B-1)/B, B, 0, stream>>>(H, x, pos, b1_lw, st2, xstats, mem1);
  k_poollin <<<(4800*16+B-1)/B, B, 0, stream>>>(mem1, p1w, p1b, g1, 4800, 16);

  // Block 2 (80x60 grid, 16->32)
  k_gmm     <<<(4800*32+B-1)/B, B, 0, stream>>>(g1, b2_lw, b2_lb, b2SK, 4800, 16, 32, stB2sk, nullptr);
  k_gmm     <<<(4800*32+B-1)/B, B, 0, stream>>>(g1, b2_c1w, nullptr, b2S, 4800, 16, 32, nullptr, nullptr);
  k_gridagg <<<(4800*32+B-1)/B, B, 0, stream>>>(b2S, b2_c1w+16*32, b2_c1b, b2H, stB2c1, 4800, 80, 60, 32, 3.f, 3.f);
  k_gmm     <<<(4800*32+B-1)/B, B, 0, stream>>>(b2H, b2_c2w, nullptr, b2S, 4800, 32, 32, nullptr, stB2c1);
  k_gridagg <<<(4800*32+B-1)/B, B, 0, stream>>>(b2S, b2_c2w+32*32, b2_c2b, b2H, stB2c2, 4800, 80, 60, 32, 3.f, 3.f);
  k_gcombine<<<(4800*32+B-1)/B, B, 0, stream>>>(b2H, b2SK, stB2c2, stB2sk, g2f, out, 4800, 32);
  k_pool2x2 <<<(1200*32+B-1)/B, B, 0, stream>>>(g2f, mem2, 80, 60, 32);
  k_poollin <<<(1200*32+B-1)/B, B, 0, stream>>>(mem2, p2w, p2b, g2p, 1200, 32);

  // Block 3 (40x30 grid, 32->64)
  k_gmm     <<<(1200*64+B-1)/B, B, 0, stream>>>(g2p, b3_lw, b3_lb, b3SK, 1200, 32, 64, stB3sk, nullptr);
  k_gmm     <<<(1200*64+B-1)/B, B, 0, stream>>>(g2p, b3_c1w, nullptr, b3S, 1200, 32, 64, nullptr, nullptr);
  k_gridagg <<<(1200*64+B-1)/B, B, 0, stream>>>(b3S, b3_c1w+32*64, b3_c1b, b3H, stB3c1, 1200, 40, 30, 64, 6.f, 6.f);
  k_gmm     <<<(1200*64+B-1)/B, B, 0, stream>>>(b3H, b3_c2w, nullptr, b3S, 1200, 64, 64, nullptr, stB3c1);
  k_gridagg <<<(1200*64+B-1)/B, B, 0, stream>>>(b3S, b3_c2w+64*64, b3_c2b, b3H, stB3c2, 1200, 40, 30, 64, 6.f, 6.f);
  k_gcombine<<<(1200*64+B-1)/B, B, 0, stream>>>(b3H, b3SK, stB3c2, stB3sk, g3f, out+153600, 1200, 64);
  k_pool2x2 <<<(300*64+B-1)/B, B, 0, stream>>>(g3f, mem3, 40, 30, 64);
  k_poollin <<<(300*64+B-1)/B, B, 0, stream>>>(mem3, p3w, p3b, g3p, 300, 64);

  // Block 4 (20x15 grid, 64->128)
  k_gmm     <<<(300*128+B-1)/B, B, 0, stream>>>(g3p, b4_lw, b4_lb, b4SK, 300, 64, 128, stB4sk, nullptr);
  k_gmm     <<<(300*128+B-1)/B, B, 0, stream>>>(g3p, b4_c1w, nullptr, b4S, 300, 64, 128, nullptr, nullptr);
  k_gridagg <<<(300*128+B-1)/B, B, 0, stream>>>(b4S, b4_c1w+64*128, b4_c1b, b4H, stB4c1, 300, 20, 15, 128, 12.f, 12.f);
  k_gmm     <<<(300*128+B-1)/B, B, 0, stream>>>(b4H, b4_c2w, nullptr, b4S, 300, 128, 128, nullptr, stB4c1);
  k_gridagg <<<(300*128+B-1)/B, B, 0, stream>>>(b4S, b4_c2w+128*128, b4_c2b, b4H, stB4c2, 300, 20, 15, 128, 12.f, 12.f);
  k_gcombine<<<(300*128+B-1)/B, B, 0, stream>>>(b4H, b4SK, stB4c2, stB4sk, nullptr, out+230400, 300, 128);
}

// Round 5
// 777.654 us; speedup vs baseline: 2.1690x; 1.4073x over previous
//
#include <hip/hip_runtime.h>

#define NN 200000
#define NE 3200000
static constexpr float EPSV = 1e-5f;

// ---------------- CSR build: 2-level bucket sort ----------------
// bucket = dst>>10  (196 buckets, each spans 1024 dsts)

__global__ void k_cnt(const int* __restrict__ ei, int* __restrict__ bktCnt){
  __shared__ int cnt[256];
  int t = threadIdx.x;
  cnt[t] = 0; __syncthreads();
  int tile = blockIdx.x*4096;
  #pragma unroll
  for (int k = 0; k < 16; ++k){
    int e = tile + k*256 + t;
    if (e < NE) atomicAdd(&cnt[ei[NE+e]>>10], 1);
  }
  __syncthreads();
  if (cnt[t]) atomicAdd(&bktCnt[t], cnt[t]);
}

__global__ void k_bktscan(const int* __restrict__ bktCnt, int* __restrict__ bktBase,
                          int* __restrict__ bktCur, int* __restrict__ off){
  __shared__ int s[256];
  int t = threadIdx.x;
  int v = bktCnt[t];   // entries >=196 are zero (memset)
  s[t] = v; __syncthreads();
  for (int o = 1; o < 256; o <<= 1){
    int xv = (t >= o) ? s[t-o] : 0;
    __syncthreads(); s[t] += xv; __syncthreads();
  }
  int excl = s[t] - v;
  bktBase[t] = excl;
  bktCur[t]  = excl;
  if (t == 0){ bktBase[256] = NE; off[NN] = NE; }
}

// tile-local multisplit append of packed (src<<10)|(dst&1023)
__global__ void k_part1(const int* __restrict__ ei, int* __restrict__ bktCur,
                        int* __restrict__ pairs){
  __shared__ int cnt[256]; __shared__ int base[256]; __shared__ int rank[256];
  int t = threadIdx.x;   // 1024 threads
  if (t < 256) cnt[t] = 0;
  __syncthreads();
  int tile = blockIdx.x*16384;
  #pragma unroll
  for (int k = 0; k < 16; ++k){
    int e = tile + k*1024 + t;
    if (e < NE) atomicAdd(&cnt[ei[NE+e]>>10], 1);
  }
  __syncthreads();
  if (t < 256){
    base[t] = cnt[t] ? atomicAdd(&bktCur[t], cnt[t]) : 0;
    rank[t] = 0;
  }
  __syncthreads();
  #pragma unroll
  for (int k = 0; k < 16; ++k){
    int e = tile + k*1024 + t;
    if (e < NE){
      int d = ei[NE+e], s = ei[e];
      int b = d >> 10;
      int r = atomicAdd(&rank[b], 1);
      pairs[base[b] + r] = (s<<10) | (d & 1023);
    }
  }
}

// per-bucket: local hist+scan -> off[], then in-window scatter of srcs
__global__ void k_part2(const int* __restrict__ pairs, const int* __restrict__ bktBase,
                        int* __restrict__ off, int* __restrict__ srcs){
  __shared__ int hist[1024]; __shared__ int cur[1024];
  int b = blockIdx.x, t = threadIdx.x;
  int p0 = bktBase[b], p1 = bktBase[b+1];
  int cntB = p1 - p0;
  int dstBase = b << 10;
  int width = min(1024, NN - dstBase);
  hist[t] = 0; __syncthreads();
  for (int i = t; i < cntB; i += 1024) atomicAdd(&hist[pairs[p0+i] & 1023], 1);
  __syncthreads();
  int h0 = hist[t];
  for (int o = 1; o < 1024; o <<= 1){
    int xv = (t >= o) ? hist[t-o] : 0;
    __syncthreads(); hist[t] += xv; __syncthreads();
  }
  int excl = hist[t] - h0;
  if (t < width) off[dstBase + t] = p0 + excl;
  cur[t] = excl; __syncthreads();
  for (int i = t; i < cntB; i += 1024){
    int v = pairs[p0+i];
    int r = atomicAdd(&cur[v & 1023], 1);
    srcs[p0 + r] = v >> 10;
  }
}

// ---------------- Block 1 (N=200000, C=16) ----------------
__global__ void k_prep1(const float* __restrict__ x, const float* __restrict__ pos,
                        const float* __restrict__ w, float* __restrict__ A,
                        float* __restrict__ xstats){
  int i = blockIdx.x*blockDim.x + threadIdx.x;
  float xf = 0.f;
  if (i < NN){
    xf = x[i];
    float px = pos[3*i], py = pos[3*i+1];
    #pragma unroll
    for (int c = 0; c < 16; ++c){
      A[i*16+c] = xf*w[c] + px*w[16+c] + py*w[32+c];
    }
  }
  __shared__ float sv[256], sq[256];
  int t = threadIdx.x;
  float v = (i < NN) ? xf : 0.f;
  sv[t] = v; sq[t] = v*v; __syncthreads();
  for (int o = 128; o > 0; o >>= 1){
    if (t < o){ sv[t]+=sv[t+o]; sq[t]+=sq[t+o]; } __syncthreads();
  }
  if (t == 0){ atomicAdd(&xstats[0], sv[0]); atomicAdd(&xstats[1], sq[0]); }
}

// CSR gather-max: 64 lanes per dst, 16 edges in flight, float4 channels.
__global__ void k_agg16w(const float4* __restrict__ A4, const int* __restrict__ srcs,
                         const int* __restrict__ off, const float* __restrict__ pos,
                         const float* __restrict__ wpos, const float* __restrict__ bias,
                         float4* __restrict__ H4){
  int t = threadIdx.x;
  int lane = t & 63;
  int d = blockIdx.x*4 + (t >> 6);
  int eidx = lane >> 2;     // 0..15
  int cg = lane & 3;        // channel group (4 ch each)
  int s0 = off[d], s1 = off[d+1];
  float NI = -__builtin_inff();
  float4 m = make_float4(NI, NI, NI, NI);
  for (int j = s0 + eidx; j < s1; j += 16){
    int s = srcs[j];
    float4 a = A4[s*4 + cg];
    m.x = fmaxf(m.x, a.x); m.y = fmaxf(m.y, a.y);
    m.z = fmaxf(m.z, a.z); m.w = fmaxf(m.w, a.w);
  }
  #pragma unroll
  for (int mask = 4; mask <= 32; mask <<= 1){
    m.x = fmaxf(m.x, __shfl_xor(m.x, mask, 64));
    m.y = fmaxf(m.y, __shfl_xor(m.y, mask, 64));
    m.z = fmaxf(m.z, __shfl_xor(m.z, mask, 64));
    m.w = fmaxf(m.w, __shfl_xor(m.w, mask, 64));
  }
  if (eidx == 0){
    float4 val = make_float4(0.f, 0.f, 0.f, 0.f);
    if (s1 > s0){
      float px = pos[3*d], py = pos[3*d+1];
      int c0 = cg*4;
      val.x = m.x + bias[c0+0] - (px*wpos[c0+0] + py*wpos[16+c0+0]);
      val.y = m.y + bias[c0+1] - (px*wpos[c0+1] + py*wpos[16+c0+1]);
      val.z = m.z + bias[c0+2] - (px*wpos[c0+2] + py*wpos[16+c0+2]);
      val.w = m.w + bias[c0+3] - (px*wpos[c0+3] + py*wpos[16+c0+3]);
    }
    H4[d*4 + cg] = val;
  }
}

__global__ void k_stats16(const float* __restrict__ H, float* __restrict__ st){
  int t = threadIdx.x;
  float s = 0.f, q = 0.f;
  for (int idx = blockIdx.x*256 + t; idx < NN*16; idx += gridDim.x*256){
    float v = H[idx]; s += v; q += v*v;
  }
  __shared__ float sv[256], sq[256];
  sv[t] = s; sq[t] = q; __syncthreads();
  for (int o = 128; o >= 16; o >>= 1){
    if (t < o){ sv[t]+=sv[t+o]; sq[t]+=sq[t+o]; } __syncthreads();
  }
  if (t < 16){ atomicAdd(&st[t], sv[t]); atomicAdd(&st[16+t], sq[t]); }
}

// A2 = relu(bn(Hraw)) @ c2w[0:16] + p . c2w[16:18], thread per (node, ch-group)
__global__ void k_prep2(const float* __restrict__ Hraw, const float* __restrict__ st1,
                        const float* __restrict__ pos, const float* __restrict__ w,
                        float4* __restrict__ A4){
  int idx = blockIdx.x*blockDim.x + threadIdx.x;
  if (idx >= NN*4) return;
  int i = idx >> 2, cg = idx & 3;
  const float inv_n = 1.f/(float)NN;
  float acc0 = 0.f, acc1 = 0.f, acc2 = 0.f, acc3 = 0.f;
  #pragma unroll
  for (int k = 0; k < 16; ++k){
    float mk = st1[k]*inv_n;
    float vk = st1[16+k]*inv_n - mk*mk;
    float ik = rsqrtf(vk + EPSV);
    float h = fmaxf((Hraw[i*16+k]-mk)*ik, 0.f);
    acc0 += h*w[k*16 + cg*4 + 0];
    acc1 += h*w[k*16 + cg*4 + 1];
    acc2 += h*w[k*16 + cg*4 + 2];
    acc3 += h*w[k*16 + cg*4 + 3];
  }
  float px = pos[3*i], py = pos[3*i+1];
  int c0 = cg*4;
  acc0 += px*w[256+c0+0] + py*w[272+c0+0];
  acc1 += px*w[256+c0+1] + py*w[272+c0+1];
  acc2 += px*w[256+c0+2] + py*w[272+c0+2];
  acc3 += px*w[256+c0+3] + py*w[272+c0+3];
  A4[idx] = make_float4(acc0, acc1, acc2, acc3);
}

// out = relu(bn(h2pre)+bn_skip) fused with pool1 atomics
__global__ void k_comb_pool(const float* __restrict__ H, const float* __restrict__ x,
                            const float* __restrict__ pos, const float* __restrict__ lw,
                            const float* __restrict__ st2, const float* __restrict__ xstats,
                            float* __restrict__ mem){
  int idx = blockIdx.x*blockDim.x + threadIdx.x;
  if (idx >= NN*4) return;
  int i = idx >> 2, cg = idx & 3;
  const float inv_n = 1.f/(float)NN;
  float mx = xstats[0]*inv_n, vx = xstats[1]*inv_n - mx*mx;
  float xc = x[i] - mx;
  float px = pos[3*i], py = pos[3*i+1];
  int cx = (int)(px * 80.f / 240.f); cx = min(max(cx,0),79);
  int cy = (int)(py * 60.f / 180.f); cy = min(max(cy,0),59);
  float* mrow = &mem[(cy*80+cx)*16 + cg*4];
  #pragma unroll
  for (int k = 0; k < 4; ++k){
    int c = cg*4 + k;
    float m2 = st2[c]*inv_n, v2 = st2[16+c]*inv_n - m2*m2;
    float i2 = rsqrtf(v2 + EPSV);
    float a = lw[c];
    float sc = a * rsqrtf(a*a*vx + EPSV);
    float v = (H[i*16+c]-m2)*i2 + xc*sc;
    v = fmaxf(v, 0.f);
    atomicAdd(&mrow[k], v);
  }
}

__global__ void k_poollin(const float* __restrict__ mem, const float* __restrict__ W,
                          const float* __restrict__ b, float* __restrict__ G,
                          int n, int C){
  int idx = blockIdx.x*blockDim.x + threadIdx.x;
  if (idx >= n*C) return;
  int i = idx / C, c = idx % C;
  float acc = b[c];
  for (int k = 0; k < C; ++k) acc += mem[i*C+k]*W[k*C+c];
  G[idx] = (acc > 1.f) ? acc : 0.f;
}

// ---------------- Grid blocks (2..4) ----------------
__global__ void k_gmm(const float* __restrict__ X, const float* __restrict__ W,
                      const float* __restrict__ bias, float* __restrict__ S,
                      int n, int K, int C, float* __restrict__ st,
                      const float* __restrict__ instats){
  int idx = blockIdx.x*blockDim.x + threadIdx.x;
  int t = threadIdx.x;
  float val = 0.f;
  const float inv_n = 1.f/(float)n;
  if (idx < n*C){
    int i = idx / C, c = idx % C;
    float acc = bias ? bias[c] : 0.f;
    for (int k = 0; k < K; ++k){
      float xk = X[i*K+k];
      if (instats){
        float mk = instats[k]*inv_n;
        float vk = instats[K+k]*inv_n - mk*mk;
        xk = fmaxf((xk-mk)*rsqrtf(vk+EPSV), 0.f);
      }
      acc += xk*W[k*C+c];
    }
    S[idx] = acc;
    val = acc;
  }
  if (st){
    __shared__ float sv[256], sq[256];
    sv[t] = val; sq[t] = val*val; __syncthreads();
    for (int o = 128; o >= C; o >>= 1){
      if (t < o){ sv[t]+=sv[t+o]; sq[t]+=sq[t+o]; } __syncthreads();
    }
    if (t < C){ atomicAdd(&st[t], sv[t]); atomicAdd(&st[C+t], sq[t]); }
  }
}

__global__ void k_gridagg(const float* __restrict__ S, const float* __restrict__ wpos,
                          const float* __restrict__ bias, float* __restrict__ H,
                          float* __restrict__ st, int n, int gw, int gh, int C,
                          float sx, float sy){
  int idx = blockIdx.x*blockDim.x + threadIdx.x;
  int t = threadIdx.x;
  float val = 0.f;
  if (idx < n*C){
    int i = idx / C, c = idx % C;
    int x = i % gw, y = i / gw;
    float wx = wpos[c], wy = wpos[C+c];
    float m = -__builtin_inff();
    for (int oy = -1; oy <= 1; ++oy){
      int ny = y + oy; if (ny < 0 || ny >= gh) continue;
      for (int ox = -1; ox <= 1; ++ox){
        int nx = x + ox; if (nx < 0 || nx >= gw) continue;
        float v = S[(ny*gw+nx)*C + c] + (ox*sx)*wx + (oy*sy)*wy;
        m = fmaxf(m, v);
      }
    }
    val = m + bias[c];
    H[idx] = val;
  }
  __shared__ float sv[256], sq[256];
  sv[t] = val; sq[t] = val*val; __syncthreads();
  for (int o = 128; o >= C; o >>= 1){
    if (t < o){ sv[t]+=sv[t+o]; sq[t]+=sq[t+o]; } __syncthreads();
  }
  if (t < C){ atomicAdd(&st[t], sv[t]); atomicAdd(&st[C+t], sq[t]); }
}

__global__ void k_gcombine(const float* __restrict__ H, const float* __restrict__ SK,
                           const float* __restrict__ st2, const float* __restrict__ stsk,
                           float* __restrict__ G, float* __restrict__ outf,
                           int n, int C){
  int idx = blockIdx.x*blockDim.x + threadIdx.x;
  if (idx >= n*C) return;
  int c = idx % C;
  float inv_n = 1.f/(float)n;
  float m2 = st2[c]*inv_n, v2 = st2[C+c]*inv_n - m2*m2;
  float i2 = rsqrtf(v2 + EPSV);
  float ms = stsk[c]*inv_n, vs = stsk[C+c]*inv_n - ms*ms;
  float is_ = rsqrtf(vs + EPSV);
  float v = (H[idx]-m2)*i2 + (SK[idx]-ms)*is_;
  v = fmaxf(v, 0.f);
  if (G) G[idx] = v;
  outf[idx] = v;
}

__global__ void k_pool2x2(const float* __restrict__ G, float* __restrict__ mem,
                          int gw, int gh, int C){
  int ow = gw >> 1;
  int n2 = ow*(gh>>1);
  int idx = blockIdx.x*blockDim.x + threadIdx.x;
  if (idx >= n2*C) return;
  int i = idx / C, c = idx % C;
  int x = i % ow, y = i / ow;
  float a0 = G[((2*y)*gw + 2*x)*C + c];
  float a1 = G[((2*y)*gw + 2*x+1)*C + c];
  float a2 = G[((2*y+1)*gw + 2*x)*C + c];
  float a3 = G[((2*y+1)*gw + 2*x+1)*C + c];
  mem[idx] = ((a0 + a1) + a2) + a3;
}

extern "C" void kernel_launch(void* const* d_in, const int* in_sizes, int n_in,
                              void* d_out, int out_size, void* d_ws, size_t ws_size,
                              hipStream_t stream){
  const float* x   = (const float*)d_in[0];
  const float* pos = (const float*)d_in[1];
  const int*   ei  = (const int*)d_in[2];
  const float* b1_c1w = (const float*)d_in[3];
  const float* b1_c1b = (const float*)d_in[4];
  const float* b1_c2w = (const float*)d_in[5];
  const float* b1_c2b = (const float*)d_in[6];
  const float* b1_lw  = (const float*)d_in[7];
  const float* b2_c1w = (const float*)d_in[9];
  const float* b2_c1b = (const float*)d_in[10];
  const float* b2_c2w = (const float*)d_in[11];
  const float* b2_c2b = (const float*)d_in[12];
  const float* b2_lw  = (const float*)d_in[13];
  const float* b2_lb  = (const float*)d_in[14];
  const float* b3_c1w = (const float*)d_in[15];
  const float* b3_c1b = (const float*)d_in[16];
  const float* b3_c2w = (const float*)d_in[17];
  const float* b3_c2b = (const float*)d_in[18];
  const float* b3_lw  = (const float*)d_in[19];
  const float* b3_lb  = (const float*)d_in[20];
  const float* b4_c1w = (const float*)d_in[21];
  const float* b4_c1b = (const float*)d_in[22];
  const float* b4_c2w = (const float*)d_in[23];
  const float* b4_c2b = (const float*)d_in[24];
  const float* b4_lw  = (const float*)d_in[25];
  const float* b4_lb  = (const float*)d_in[26];
  const float* p1w = (const float*)d_in[27];
  const float* p1b = (const float*)d_in[28];
  const float* p2w = (const float*)d_in[29];
  const float* p2b = (const float*)d_in[30];
  const float* p3w = (const float*)d_in[31];
  const float* p3b = (const float*)d_in[32];
  float* out = (float*)d_out;

  // ---- workspace carve: floats first (16B alignment) ----
  float* A  = (float*)d_ws;          // NN*16 (12.8MB); pairs aliases (dead before A)
  int* pairs = (int*)A;              // NE ints — ALIAS
  float* H  = A + NN*16;             // NN*16
  float* ST = H + NN*16;             // 2048 floats
  float* xstats = ST;
  float* st1    = ST + 16;
  float* st2    = ST + 64;
  float* stB2sk = ST + 128;
  float* stB2c1 = ST + 192;
  float* stB2c2 = ST + 256;
  float* stB3sk = ST + 320;
  float* stB3c1 = ST + 448;
  float* stB3c2 = ST + 576;
  float* stB4sk = ST + 704;
  float* stB4c1 = ST + 960;
  float* stB4c2 = ST + 1216;
  float* SM   = ST + 2048;
  float* mem1 = SM;                  // 4800*16
  float* g1   = mem1 + 76800;
  float* b2S  = g1 + 76800;          // 4800*32
  float* b2SK = b2S + 153600;
  float* b2H  = b2SK + 153600;
  float* g2f  = b2H + 153600;
  float* mem2 = g2f + 153600;        // 1200*32
  float* g2p  = mem2 + 38400;
  float* b3S  = g2p + 38400;         // 1200*64
  float* b3SK = b3S + 76800;
  float* b3H  = b3SK + 76800;
  float* g3f  = b3H + 76800;
  float* mem3 = g3f + 76800;         // 300*64
  float* g3p  = mem3 + 19200;
  float* b4S  = g3p + 19200;         // 300*128
  float* b4SK = b4S + 38400;
  float* b4H  = b4SK + 38400;        // end floats
  int* off     = (int*)(b4H + 38400);  // NN+1
  int* srcs    = off + (NN+1);         // NE
  int* bktCnt  = srcs + NE;            // 256
  int* bktBase = bktCnt + 256;         // 257
  int* bktCur  = bktBase + 257;        // 256

  hipMemsetAsync(bktCnt, 0, 256*sizeof(int), stream);
  hipMemsetAsync(ST, 0, 2048*sizeof(float), stream);
  hipMemsetAsync(mem1, 0, 76800*sizeof(float), stream);

  const int B = 256;
  // CSR build (2-level bucket sort)
  k_cnt    <<<(NE+4095)/4096, 256, 0, stream>>>(ei, bktCnt);
  k_bktscan<<<1, 256, 0, stream>>>(bktCnt, bktBase, bktCur, off);
  k_part1  <<<(NE+16383)/16384, 1024, 0, stream>>>(ei, bktCur, pairs);
  k_part2  <<<196, 1024, 0, stream>>>(pairs, bktBase, off, srcs);

  // Block 1
  k_prep1   <<<(NN+B-1)/B, B, 0, stream>>>(x, pos, b1_c1w, A, xstats);
  k_agg16w  <<<NN/4, B, 0, stream>>>((const float4*)A, srcs, off, pos, b1_c1w+16, b1_c1b, (float4*)H);
  k_stats16 <<<256, B, 0, stream>>>(H, st1);
  k_prep2   <<<(NN*4+B-1)/B, B, 0, stream>>>(H, st1, pos, b1_c2w, (float4*)A);
  k_agg16w  <<<NN/4, B, 0, stream>>>((const float4*)A, srcs, off, pos, b1_c2w+256, b1_c2b, (float4*)H);
  k_stats16 <<<256, B, 0, stream>>>(H, st2);
  k_comb_pool<<<(NN*4+B-1)/B, B, 0, stream>>>(H, x, pos, b1_lw, st2, xstats, mem1);
  k_poollin <<<(4800*16+B-1)/B, B, 0, stream>>>(mem1, p1w, p1b, g1, 4800, 16);

  // Block 2 (80x60 grid, 16->32)
  k_gmm     <<<(4800*32+B-1)/B, B, 0, stream>>>(g1, b2_lw, b2_lb, b2SK, 4800, 16, 32, stB2sk, nullptr);
  k_gmm     <<<(4800*32+B-1)/B, B, 0, stream>>>(g1, b2_c1w, nullptr, b2S, 4800, 16, 32, nullptr, nullptr);
  k_gridagg <<<(4800*32+B-1)/B, B, 0, stream>>>(b2S, b2_c1w+16*32, b2_c1b, b2H, stB2c1, 4800, 80, 60, 32, 3.f, 3.f);
  k_gmm     <<<(4800*32+B-1)/B, B, 0, stream>>>(b2H, b2_c2w, nullptr, b2S, 4800, 32, 32, nullptr, stB2c1);
  k_gridagg <<<(4800*32+B-1)/B, B, 0, stream>>>(b2S, b2_c2w+32*32, b2_c2b, b2H, stB2c2, 4800, 80, 60, 32, 3.f, 3.f);
  k_gcombine<<<(4800*32+B-1)/B, B, 0, stream>>>(b2H, b2SK, stB2c2, stB2sk, g2f, out, 4800, 32);
  k_pool2x2 <<<(1200*32+B-1)/B, B, 0, stream>>>(g2f, mem2, 80, 60, 32);
  k_poollin <<<(1200*32+B-1)/B, B, 0, stream>>>(mem2, p2w, p2b, g2p, 1200, 32);

  // Block 3 (40x30 grid, 32->64)
  k_gmm     <<<(1200*64+B-1)/B, B, 0, stream>>>(g2p, b3_lw, b3_lb, b3SK, 1200, 32, 64, stB3sk, nullptr);
  k_gmm     <<<(1200*64+B-1)/B, B, 0, stream>>>(g2p, b3_c1w, nullptr, b3S, 1200, 32, 64, nullptr, nullptr);
  k_gridagg <<<(1200*64+B-1)/B, B, 0, stream>>>(b3S, b3_c1w+32*64, b3_c1b, b3H, stB3c1, 1200, 40, 30, 64, 6.f, 6.f);
  k_gmm     <<<(1200*64+B-1)/B, B, 0, stream>>>(b3H, b3_c2w, nullptr, b3S, 1200, 64, 64, nullptr, stB3c1);
  k_gridagg <<<(1200*64+B-1)/B, B, 0, stream>>>(b3S, b3_c2w+64*64, b3_c2b, b3H, stB3c2, 1200, 40, 30, 64, 6.f, 6.f);
  k_gcombine<<<(1200*64+B-1)/B, B, 0, stream>>>(b3H, b3SK, stB3c2, stB3sk, g3f, out+153600, 1200, 64);
  k_pool2x2 <<<(300*64+B-1)/B, B, 0, stream>>>(g3f, mem3, 40, 30, 64);
  k_poollin <<<(300*64+B-1)/B, B, 0, stream>>>(mem3, p3w, p3b, g3p, 300, 64);

  // Block 4 (20x15 grid, 64->128)
  k_gmm     <<<(300*128+B-1)/B, B, 0, stream>>>(g3p, b4_lw, b4_lb, b4SK, 300, 64, 128, stB4sk, nullptr);
  k_gmm     <<<(300*128+B-1)/B, B, 0, stream>>>(g3p, b4_c1w, nullptr, b4S, 300, 64, 128, nullptr, nullptr);
  k_gridagg <<<(300*128+B-1)/B, B, 0, stream>>>(b4S, b4_c1w+64*128, b4_c1b, b4H, stB4c1, 300, 20, 15, 128, 12.f, 12.f);
  k_gmm     <<<(300*128+B-1)/B, B, 0, stream>>>(b4H, b4_c2w, nullptr, b4S, 300, 128, 128, nullptr, stB4c1);
  k_gridagg <<<(300*128+B-1)/B, B, 0, stream>>>(b4S, b4_c2w+128*128, b4_c2b, b4H, stB4c2, 300, 20, 15, 128, 12.f, 12.f);
  k_gcombine<<<(300*128+B-1)/B, B, 0, stream>>>(b4H, b4SK, stB4c2, stB4sk, nullptr, out+230400, 300, 128);
}